// Round 10
// baseline (345.427 us; speedup 1.0000x reference)
//
#include <hip/hip_runtime.h>
#include <hip/hip_bf16.h>

#define N_NODES 100000
#define N_EDGES 1250000
#define HID 64
#define LDSS 72     // LDS row stride in bf16 elems: 64 + 8 pad (144 B rows)
#define NB 196      // buckets of 512 node-ids: (100000+511)/512
#define NBLOCK 128  // edge-slice blocks for P1/P3 (per (block,bucket) ~50 edges)

typedef __bf16 bf16x8 __attribute__((ext_vector_type(8)));
typedef float  f32x4  __attribute__((ext_vector_type(4)));

__device__ __forceinline__ float bf2f(ushort u) {
    union { unsigned int i; float f; } v; v.i = ((unsigned int)u) << 16; return v.f;
}
__device__ __forceinline__ ushort f2bf(float f) {
    union { float f; unsigned int i; } v; v.f = f;
    unsigned int x = v.i;
    return (ushort)((x + 0x7fffu + ((x >> 16) & 1u)) >> 16);  // RNE
}

// h0[i][:] = bf16(emb[x[i]][:])  — emb f32, h0 bf16. 4 f32 per thread.
__global__ __launch_bounds__(256) void embed_gather(const int* __restrict__ x,
                                                    const float* __restrict__ emb,
                                                    ushort* __restrict__ h0) {
    int t = blockIdx.x * 256 + threadIdx.x;
    if (t >= N_NODES * 16) return;
    int row = t >> 4, c = t & 15;
    int idx = x[row];
    float4 v = ((const float4*)(emb + (size_t)idx * HID))[c];
    ushort4 w;
    w.x = f2bf(v.x); w.y = f2bf(v.y); w.z = f2bf(v.z); w.w = f2bf(v.w);
    ((ushort4*)(h0 + (size_t)row * HID))[c] = w;
}

// One-time weight conversion: wbf[m][n*64+k] = bf16(W_m[k*64+n]) (transposed,
// n-major — the exact layout gemm blocks stage). 5 matrices, 1 block each.
__global__ __launch_bounds__(256) void wcvt(const float* __restrict__ Wl1,
                                            const float* __restrict__ Wr1,
                                            const float* __restrict__ Wl2,
                                            const float* __restrict__ Wr2,
                                            const float* __restrict__ Wout,
                                            ushort* __restrict__ wbf) {
    const float* W = (blockIdx.x == 0) ? Wl1 : (blockIdx.x == 1) ? Wr1 :
                     (blockIdx.x == 2) ? Wl2 : (blockIdx.x == 3) ? Wr2 : Wout;
    ushort* o = wbf + blockIdx.x * 4096;
    for (int idx = threadIdx.x; idx < 4096; idx += 256) {
        int k = idx >> 6, n = idx & 63;   // coalesced read W[k][n]
        o[n * 64 + k] = f2bf(W[idx]);     // scatter write (tiny kernel, fine)
    }
}

// ---- atomic-free CSR build: bucket counting sort, all atomics in LDS ----

__global__ __launch_bounds__(256) void p1_hist(const int* __restrict__ dst,
                                               int* __restrict__ gh) {
    __shared__ int hist[NB];
    const int tid = threadIdx.x;
    for (int i = tid; i < NB; i += 256) hist[i] = 0;
    __syncthreads();
    for (int e = blockIdx.x * 256 + tid; e < N_EDGES; e += NBLOCK * 256)
        atomicAdd(&hist[dst[e] >> 9], 1);
    __syncthreads();
    for (int i = tid; i < NB; i += 256) gh[blockIdx.x * NB + i] = hist[i];
}

__global__ __launch_bounds__(128) void p2_scan(int* __restrict__ gh,
                                               int* __restrict__ btot) {
    __shared__ int w0tot;
    const int v = blockIdx.x;
    const int t = threadIdx.x, lane = t & 63, wave = t >> 6;
    int val = gh[t * NB + v];
    int x = val;
#pragma unroll
    for (int d = 1; d < 64; d <<= 1) {
        int y = __shfl_up(x, d, 64);
        if (lane >= d) x += y;
    }
    if (wave == 0 && lane == 63) w0tot = x;
    __syncthreads();
    int excl = (x - val) + (wave == 1 ? w0tot : 0);
    gh[t * NB + v] = excl;
    if (wave == 1 && lane == 63) btot[v] = excl + val;
}

__global__ __launch_bounds__(256) void p2b_scan(const int* __restrict__ btot,
                                                int* __restrict__ bstart) {
    __shared__ int wsum[4];
    const int t = threadIdx.x, lane = t & 63, wave = t >> 6;
    int v = (t < NB) ? btot[t] : 0;
    int x = v;
#pragma unroll
    for (int d = 1; d < 64; d <<= 1) {
        int y = __shfl_up(x, d, 64);
        if (lane >= d) x += y;
    }
    if (lane == 63) wsum[wave] = x;
    __syncthreads();
    if (wave == 0) {
        int s = (lane < 4) ? wsum[lane] : 0;
#pragma unroll
        for (int d = 1; d < 4; d <<= 1) {
            int y = __shfl_up(s, d, 64);
            if (lane >= d) s += y;
        }
        if (lane < 4) wsum[lane] = s;
    }
    __syncthreads();
    int waveoff = (wave == 0) ? 0 : wsum[wave - 1];
    int excl = waveoff + (x - v);
    if (t < NB) bstart[t] = excl;
    if (t == 0) bstart[NB] = N_EDGES;
}

__global__ __launch_bounds__(256) void p3_scatter(const int* __restrict__ src,
                                                  const int* __restrict__ dst,
                                                  const int* __restrict__ gh,
                                                  const int* __restrict__ bstart,
                                                  uint* __restrict__ ebuf) {
    __shared__ int base[NB];
    __shared__ int run[NB];
    const int tid = threadIdx.x;
    for (int i = tid; i < NB; i += 256) {
        base[i] = bstart[i] + gh[blockIdx.x * NB + i];
        run[i] = 0;
    }
    __syncthreads();
    for (int e = blockIdx.x * 256 + tid; e < N_EDGES; e += NBLOCK * 256) {
        int d = dst[e];
        int v = d >> 9;
        int r = atomicAdd(&run[v], 1);
        ebuf[base[v] + r] = ((uint)(d & 511) << 17) | (uint)src[e];
    }
}

__global__ __launch_bounds__(256) void p4_csr(const uint* __restrict__ ebuf,
                                              const int* __restrict__ bstart,
                                              int* __restrict__ rowptr,
                                              int* __restrict__ csr_src) {
    __shared__ int hist[512], hoff[512], run[512];
    __shared__ int wsum[4];
    const int v = blockIdx.x;
    const int tid = threadIdx.x, lane = tid & 63, wave = tid >> 6;
    const int node0 = v << 9;
    const int nn = min(512, N_NODES - node0);
    const int beg = bstart[v], end = bstart[v + 1];

    for (int i = tid; i < 512; i += 256) { hist[i] = 0; run[i] = 0; }
    __syncthreads();
    for (int e = beg + tid; e < end; e += 256)
        atomicAdd(&hist[ebuf[e] >> 17], 1);
    __syncthreads();
    int h0 = hist[2 * tid], h1 = hist[2 * tid + 1];
    int s = h0 + h1;
    int x = s;
#pragma unroll
    for (int d = 1; d < 64; d <<= 1) {
        int y = __shfl_up(x, d, 64);
        if (lane >= d) x += y;
    }
    if (lane == 63) wsum[wave] = x;
    __syncthreads();
    if (wave == 0) {
        int s2 = (lane < 4) ? wsum[lane] : 0;
#pragma unroll
        for (int d = 1; d < 4; d <<= 1) {
            int y = __shfl_up(s2, d, 64);
            if (lane >= d) s2 += y;
        }
        if (lane < 4) wsum[lane] = s2;
    }
    __syncthreads();
    int waveoff = (wave == 0) ? 0 : wsum[wave - 1];
    int excl = waveoff + (x - s);
    hoff[2 * tid] = excl;
    hoff[2 * tid + 1] = excl + h0;
    __syncthreads();
    for (int j = tid; j < nn; j += 256) rowptr[node0 + j] = beg + hoff[j];
    if (v == NB - 1 && tid == 0) rowptr[N_NODES] = N_EDGES;
    for (int e = beg + tid; e < end; e += 256) {
        uint p = ebuf[e];
        int dl = p >> 17;
        int r = atomicAdd(&run[dl], 1);
        csr_src[beg + hoff[dl] + r] = (int)(p & 0x1FFFFu);
    }
}

// Fused SAGE layer: aggregate means for this block's 64 rows directly into the
// sA LDS tile (no meanb round-trip), then MFMA:
//   out = [DO_AGG: mean@Wl +] bl + hin@Wr, optional PReLU.
// Weights arrive pre-transposed bf16 ([n][k], from wcvt).
template <bool DO_AGG, bool HAS_PRELU, bool OUT_F32>
__global__ __launch_bounds__(256) void gemm_fused(const int* __restrict__ rowptr,
                                                  const int* __restrict__ csr_src,
                                                  const ushort* __restrict__ hin,
                                                  const ushort* __restrict__ wl_bf,
                                                  const float* __restrict__ bl,
                                                  const ushort* __restrict__ wr_bf,
                                                  const float* __restrict__ alpha_p,
                                                  void* __restrict__ out_p, int n) {
    __shared__ __align__(16) ushort sA[DO_AGG ? 64 : 1][LDSS];
    __shared__ __align__(16) ushort sH[64][LDSS];
    __shared__ __align__(16) ushort sWl[DO_AGG ? 64 : 1][LDSS];
    __shared__ __align__(16) ushort sWr[64][LDSS];

    const int tid = threadIdx.x;
    const int row0 = blockIdx.x * 64;
    const int lane = tid & 63;
    const int wave = tid >> 6;

    // stage weights + h tile, all uint4 (8 bf16 per chunk)
    for (int c = tid; c < 512; c += 256) {
        int nr = c >> 3, kc = (c & 7) * 8;
        *(uint4*)&sWr[nr][kc] = *(const uint4*)&wr_bf[nr * 64 + kc];
        if (DO_AGG) *(uint4*)&sWl[nr][kc] = *(const uint4*)&wl_bf[nr * 64 + kc];
    }
    for (int c = tid; c < 512; c += 256) {
        int r = c >> 3, dc = (c & 7) * 8;
        int g = row0 + r;
        uint4 v = {0, 0, 0, 0};
        if (g < n) v = *(const uint4*)&hin[(size_t)g * HID + dc];
        *(uint4*)&sH[r][dc] = v;
    }

    if (DO_AGG) {
        // wave w aggregates rows w*16..w*16+15; per node: 8 edge slots (octet q)
        // x 8 lanes (dim group gg), uint4 row gathers, shfl_xor combine.
        const int q = lane >> 3;
        const int gg = lane & 7;
        for (int r = 0; r < 16; ++r) {
            int row = wave * 16 + r;
            int node = row0 + row;
            float a[8] = {};
            int beg = 0, end = 0;
            if (node < n) { beg = rowptr[node]; end = rowptr[node + 1]; }
            for (int i = beg; i < end; i += 8) {
                int e = i + q;
                if (e < end) {
                    int s = csr_src[e];
                    uint4 w = *(const uint4*)&hin[(size_t)s * HID + gg * 8];
                    a[0] += bf2f((ushort)(w.x & 0xffff)); a[1] += bf2f((ushort)(w.x >> 16));
                    a[2] += bf2f((ushort)(w.y & 0xffff)); a[3] += bf2f((ushort)(w.y >> 16));
                    a[4] += bf2f((ushort)(w.z & 0xffff)); a[5] += bf2f((ushort)(w.z >> 16));
                    a[6] += bf2f((ushort)(w.w & 0xffff)); a[7] += bf2f((ushort)(w.w >> 16));
                }
            }
#pragma unroll
            for (int j = 0; j < 8; ++j) {
                a[j] += __shfl_xor(a[j], 8, 64);
                a[j] += __shfl_xor(a[j], 16, 64);
                a[j] += __shfl_xor(a[j], 32, 64);
            }
            if (lane < 8) {
                float inv = (end > beg) ? 1.0f / (float)(end - beg) : 0.f;
                uint4 o;
                o.x = (uint)f2bf(a[0] * inv) | ((uint)f2bf(a[1] * inv) << 16);
                o.y = (uint)f2bf(a[2] * inv) | ((uint)f2bf(a[3] * inv) << 16);
                o.z = (uint)f2bf(a[4] * inv) | ((uint)f2bf(a[5] * inv) << 16);
                o.w = (uint)f2bf(a[6] * inv) | ((uint)f2bf(a[7] * inv) << 16);
                *(uint4*)&sA[row][lane * 8] = o;
            }
        }
    }
    __syncthreads();

    const int quad = lane >> 4;
    const int lr = lane & 15;
    const int r0 = wave * 16;
    const float alpha = HAS_PRELU ? alpha_p[0] : 0.f;

    for (int nt = 0; nt < 4; ++nt) {
        f32x4 acc = {0.f, 0.f, 0.f, 0.f};
#pragma unroll
        for (int ks = 0; ks < 2; ++ks) {
            int k0 = ks * 32 + quad * 8;
            bf16x8 hf = *(const bf16x8*)&sH[r0 + lr][k0];
            bf16x8 wr = *(const bf16x8*)&sWr[nt * 16 + lr][k0];
            acc = __builtin_amdgcn_mfma_f32_16x16x32_bf16(hf, wr, acc, 0, 0, 0);
            if (DO_AGG) {
                bf16x8 af = *(const bf16x8*)&sA[r0 + lr][k0];
                bf16x8 wl = *(const bf16x8*)&sWl[nt * 16 + lr][k0];
                acc = __builtin_amdgcn_mfma_f32_16x16x32_bf16(af, wl, acc, 0, 0, 0);
            }
        }
        int col = nt * 16 + lr;
        float bias = bl[col];
#pragma unroll
        for (int r = 0; r < 4; ++r) {
            int row = r0 + quad * 4 + r;  // C/D: col=lane&15, row=(lane>>4)*4+reg [m89]
            int g = row0 + row;
            if (g < n) {
                float v = acc[r] + bias;
                if (HAS_PRELU) v = (v >= 0.f) ? v : alpha * v;
                if (OUT_F32)
                    ((float*)out_p)[(size_t)g * HID + col] = v;
                else
                    ((ushort*)out_p)[(size_t)g * HID + col] = f2bf(v);
            }
        }
    }
}

extern "C" void kernel_launch(void* const* d_in, const int* in_sizes, int n_in,
                              void* d_out, int out_size, void* d_ws, size_t ws_size,
                              hipStream_t stream) {
    const int*   x    = (const int*)d_in[0];
    const int*   src  = (const int*)d_in[1];
    const int*   dst  = src + N_EDGES;
    const float* emb  = (const float*)d_in[3];
    const float* Wl1  = (const float*)d_in[4];
    const float* bl1  = (const float*)d_in[5];
    const float* Wr1  = (const float*)d_in[6];
    const float* a1   = (const float*)d_in[7];
    const float* Wl2  = (const float*)d_in[8];
    const float* bl2  = (const float*)d_in[9];
    const float* Wr2  = (const float*)d_in[10];
    const float* a2   = (const float*)d_in[11];
    const float* Wout = (const float*)d_in[12];
    const float* bout = (const float*)d_in[13];

    char* ws = (char*)d_ws;
    int*    gh      = (int*)ws;                      // 100,352 (pad 100,416)
    int*    btot    = (int*)(ws + 100416);           // 832
    int*    bstart  = (int*)(ws + 101248);           // 832
    int*    rowptr  = (int*)(ws + 102080);           // 400,064
    ushort* wbf     = (ushort*)(ws + 502144);        // 5*8192 = 40,960
    uint*   ebuf    = (uint*)(ws + 543104);          // 5,000,000
    int*    csr_src = (int*)(ws + 5543104);          // 5,000,000
    ushort* h0      = (ushort*)(ws + 10543104);      // 12.8 MB
    ushort* h1      = (ushort*)(ws + 23343104);      // 12.8 MB (end: 36.1 MB)
    ushort* h2      = h0;                            // h0 dead after layer-1

    ushort* wl1b = wbf;
    ushort* wr1b = wbf + 4096;
    ushort* wl2b = wbf + 8192;
    ushort* wr2b = wbf + 12288;
    ushort* woutb = wbf + 16384;

    const int gemm_blocks = (N_NODES + 63) / 64;     // 1563

    embed_gather<<<(N_NODES * 16 + 255) / 256, 256, 0, stream>>>(x, emb, h0);
    wcvt<<<5, 256, 0, stream>>>(Wl1, Wr1, Wl2, Wr2, Wout, wbf);
    p1_hist<<<NBLOCK, 256, 0, stream>>>(dst, gh);
    p2_scan<<<NB, 128, 0, stream>>>(gh, btot);
    p2b_scan<<<1, 256, 0, stream>>>(btot, bstart);
    p3_scatter<<<NBLOCK, 256, 0, stream>>>(src, dst, gh, bstart, ebuf);
    p4_csr<<<NB, 256, 0, stream>>>(ebuf, bstart, rowptr, csr_src);

    // layer 1 (fused agg + gemm + prelu)
    gemm_fused<true, true, false><<<gemm_blocks, 256, 0, stream>>>(
        rowptr, csr_src, h0, wl1b, bl1, wr1b, a1, h1, N_NODES);
    // layer 2
    gemm_fused<true, true, false><<<gemm_blocks, 256, 0, stream>>>(
        rowptr, csr_src, h1, wl2b, bl2, wr2b, a2, h2, N_NODES);
    // output projection: float32 output
    gemm_fused<false, false, true><<<gemm_blocks, 256, 0, stream>>>(
        rowptr, csr_src, h2, woutb, bout, woutb, a1, d_out, N_NODES);
}

// Round 11
// 288.823 us; speedup vs baseline: 1.1960x; 1.1960x over previous
//
#include <hip/hip_runtime.h>
#include <hip/hip_bf16.h>

#define N_NODES 100000
#define N_EDGES 1250000
#define HID 64
#define LDSS 72     // LDS row stride in bf16 elems: 64 + 8 pad (144 B rows)
#define NB 196      // buckets of 512 node-ids: (100000+511)/512
#define NBLOCK 128  // edge-slice blocks for P1/P3

typedef __bf16 bf16x8 __attribute__((ext_vector_type(8)));
typedef float  f32x4  __attribute__((ext_vector_type(4)));

__device__ __forceinline__ float bf2f(ushort u) {
    union { unsigned int i; float f; } v; v.i = ((unsigned int)u) << 16; return v.f;
}
__device__ __forceinline__ float bflo(uint u) {   // low bf16 of a packed uint -> f32
    union { unsigned int i; float f; } v; v.i = u << 16; return v.f;
}
__device__ __forceinline__ float bfhi(uint u) {   // high bf16 -> f32
    union { unsigned int i; float f; } v; v.i = u & 0xFFFF0000u; return v.f;
}
__device__ __forceinline__ ushort f2bf(float f) {
    union { float f; unsigned int i; } v; v.f = f;
    unsigned int x = v.i;
    return (ushort)((x + 0x7fffu + ((x >> 16) & 1u)) >> 16);  // RNE
}

// h0[i][:] = bf16(emb[x[i]][:])  — emb f32, h0 bf16. 4 f32 per thread.
__global__ __launch_bounds__(256) void embed_gather(const int* __restrict__ x,
                                                    const float* __restrict__ emb,
                                                    ushort* __restrict__ h0) {
    int t = blockIdx.x * 256 + threadIdx.x;
    if (t >= N_NODES * 16) return;
    int row = t >> 4, c = t & 15;
    int idx = x[row];
    float4 v = ((const float4*)(emb + (size_t)idx * HID))[c];
    ushort4 w;
    w.x = f2bf(v.x); w.y = f2bf(v.y); w.z = f2bf(v.z); w.w = f2bf(v.w);
    ((ushort4*)(h0 + (size_t)row * HID))[c] = w;
}

// One-time weight conversion: wbf[m][n*64+k] = bf16(W_m[k*64+n]) (transposed).
__global__ __launch_bounds__(256) void wcvt(const float* __restrict__ Wl1,
                                            const float* __restrict__ Wr1,
                                            const float* __restrict__ Wl2,
                                            const float* __restrict__ Wr2,
                                            const float* __restrict__ Wout,
                                            ushort* __restrict__ wbf) {
    const float* W = (blockIdx.x == 0) ? Wl1 : (blockIdx.x == 1) ? Wr1 :
                     (blockIdx.x == 2) ? Wl2 : (blockIdx.x == 3) ? Wr2 : Wout;
    ushort* o = wbf + blockIdx.x * 4096;
    for (int idx = threadIdx.x; idx < 4096; idx += 256) {
        int k = idx >> 6, n = idx & 63;   // coalesced read W[k][n]
        o[n * 64 + k] = f2bf(W[idx]);
    }
}

// ---- atomic-free CSR build: bucket counting sort, all atomics in LDS ----

__global__ __launch_bounds__(256) void p1_hist(const int* __restrict__ dst,
                                               int* __restrict__ gh) {
    __shared__ int hist[NB];
    const int tid = threadIdx.x;
    for (int i = tid; i < NB; i += 256) hist[i] = 0;
    __syncthreads();
    for (int e = blockIdx.x * 256 + tid; e < N_EDGES; e += NBLOCK * 256)
        atomicAdd(&hist[dst[e] >> 9], 1);
    __syncthreads();
    for (int i = tid; i < NB; i += 256) gh[blockIdx.x * NB + i] = hist[i];
}

__global__ __launch_bounds__(128) void p2_scan(int* __restrict__ gh,
                                               int* __restrict__ btot) {
    __shared__ int w0tot;
    const int v = blockIdx.x;
    const int t = threadIdx.x, lane = t & 63, wave = t >> 6;
    int val = gh[t * NB + v];
    int x = val;
#pragma unroll
    for (int d = 1; d < 64; d <<= 1) {
        int y = __shfl_up(x, d, 64);
        if (lane >= d) x += y;
    }
    if (wave == 0 && lane == 63) w0tot = x;
    __syncthreads();
    int excl = (x - val) + (wave == 1 ? w0tot : 0);
    gh[t * NB + v] = excl;
    if (wave == 1 && lane == 63) btot[v] = excl + val;
}

__global__ __launch_bounds__(256) void p2b_scan(const int* __restrict__ btot,
                                                int* __restrict__ bstart) {
    __shared__ int wsum[4];
    const int t = threadIdx.x, lane = t & 63, wave = t >> 6;
    int v = (t < NB) ? btot[t] : 0;
    int x = v;
#pragma unroll
    for (int d = 1; d < 64; d <<= 1) {
        int y = __shfl_up(x, d, 64);
        if (lane >= d) x += y;
    }
    if (lane == 63) wsum[wave] = x;
    __syncthreads();
    if (wave == 0) {
        int s = (lane < 4) ? wsum[lane] : 0;
#pragma unroll
        for (int d = 1; d < 4; d <<= 1) {
            int y = __shfl_up(s, d, 64);
            if (lane >= d) s += y;
        }
        if (lane < 4) wsum[lane] = s;
    }
    __syncthreads();
    int waveoff = (wave == 0) ? 0 : wsum[wave - 1];
    int excl = waveoff + (x - v);
    if (t < NB) bstart[t] = excl;
    if (t == 0) bstart[NB] = N_EDGES;
}

__global__ __launch_bounds__(256) void p3_scatter(const int* __restrict__ src,
                                                  const int* __restrict__ dst,
                                                  const int* __restrict__ gh,
                                                  const int* __restrict__ bstart,
                                                  uint* __restrict__ ebuf) {
    __shared__ int base[NB];
    __shared__ int run[NB];
    const int tid = threadIdx.x;
    for (int i = tid; i < NB; i += 256) {
        base[i] = bstart[i] + gh[blockIdx.x * NB + i];
        run[i] = 0;
    }
    __syncthreads();
    for (int e = blockIdx.x * 256 + tid; e < N_EDGES; e += NBLOCK * 256) {
        int d = dst[e];
        int v = d >> 9;
        int r = atomicAdd(&run[v], 1);
        ebuf[base[v] + r] = ((uint)(d & 511) << 17) | (uint)src[e];
    }
}

__global__ __launch_bounds__(256) void p4_csr(const uint* __restrict__ ebuf,
                                              const int* __restrict__ bstart,
                                              int* __restrict__ rowptr,
                                              int* __restrict__ csr_src) {
    __shared__ int hist[512], hoff[512], run[512];
    __shared__ int wsum[4];
    const int v = blockIdx.x;
    const int tid = threadIdx.x, lane = tid & 63, wave = tid >> 6;
    const int node0 = v << 9;
    const int nn = min(512, N_NODES - node0);
    const int beg = bstart[v], end = bstart[v + 1];

    for (int i = tid; i < 512; i += 256) { hist[i] = 0; run[i] = 0; }
    __syncthreads();
    for (int e = beg + tid; e < end; e += 256)
        atomicAdd(&hist[ebuf[e] >> 17], 1);
    __syncthreads();
    int h0 = hist[2 * tid], h1 = hist[2 * tid + 1];
    int s = h0 + h1;
    int x = s;
#pragma unroll
    for (int d = 1; d < 64; d <<= 1) {
        int y = __shfl_up(x, d, 64);
        if (lane >= d) x += y;
    }
    if (lane == 63) wsum[wave] = x;
    __syncthreads();
    if (wave == 0) {
        int s2 = (lane < 4) ? wsum[lane] : 0;
#pragma unroll
        for (int d = 1; d < 4; d <<= 1) {
            int y = __shfl_up(s2, d, 64);
            if (lane >= d) s2 += y;
        }
        if (lane < 4) wsum[lane] = s2;
    }
    __syncthreads();
    int waveoff = (wave == 0) ? 0 : wsum[wave - 1];
    int excl = waveoff + (x - s);
    hoff[2 * tid] = excl;
    hoff[2 * tid + 1] = excl + h0;
    __syncthreads();
    for (int j = tid; j < nn; j += 256) rowptr[node0 + j] = beg + hoff[j];
    if (v == NB - 1 && tid == 0) rowptr[N_NODES] = N_EDGES;
    for (int e = beg + tid; e < end; e += 256) {
        uint p = ebuf[e];
        int dl = p >> 17;
        int r = atomicAdd(&run[dl], 1);
        csr_src[beg + hoff[dl] + r] = (int)(p & 0x1FFFFu);
    }
}

// mean[node][:] = (1/deg) * sum_{s in N(node)} h[s][:]; 0 if deg==0.
// 8 nodes per wave: each 8-lane group owns one node; lane holds 8 dims (uint4).
// Zero cross-lane shuffles; group's 8 lanes cover the full 128-B row.
__global__ __launch_bounds__(256) void agg_mean(const int* __restrict__ rowptr,
                                                const int* __restrict__ csr_src,
                                                const ushort* __restrict__ h,
                                                ushort* __restrict__ mean) {
    int node = blockIdx.x * 32 + (threadIdx.x >> 3);
    if (node >= N_NODES) return;
    const int gg = threadIdx.x & 7;   // dim group: dims 8gg..8gg+7
    int beg = rowptr[node], end = rowptr[node + 1];
    float a0 = 0.f, a1 = 0.f, a2 = 0.f, a3 = 0.f;
    float a4 = 0.f, a5 = 0.f, a6 = 0.f, a7 = 0.f;
    for (int i = beg; i < end; ++i) {
        int s = csr_src[i];               // broadcast within the 8-lane group
        uint4 w = *(const uint4*)&h[(size_t)s * HID + gg * 8];
        a0 += bflo(w.x); a1 += bfhi(w.x);
        a2 += bflo(w.y); a3 += bfhi(w.y);
        a4 += bflo(w.z); a5 += bfhi(w.z);
        a6 += bflo(w.w); a7 += bfhi(w.w);
    }
    float inv = (end > beg) ? 1.0f / (float)(end - beg) : 0.f;
    uint4 o;
    o.x = (uint)f2bf(a0 * inv) | ((uint)f2bf(a1 * inv) << 16);
    o.y = (uint)f2bf(a2 * inv) | ((uint)f2bf(a3 * inv) << 16);
    o.z = (uint)f2bf(a4 * inv) | ((uint)f2bf(a5 * inv) << 16);
    o.w = (uint)f2bf(a6 * inv) | ((uint)f2bf(a7 * inv) << 16);
    *(uint4*)&mean[(size_t)node * HID + gg * 8] = o;
}

// out = [HAS_MEAN: mean@Wl +] bl + hin@Wr, optional PReLU.
// MFMA 16x16x32 bf16: 64 rows/block, 4 waves. Weights pre-converted bf16 [n][k].
template <bool HAS_MEAN, bool HAS_PRELU, bool OUT_F32>
__global__ __launch_bounds__(256) void gemm_mfma(const ushort* __restrict__ mean,
                                                 const ushort* __restrict__ hin,
                                                 const ushort* __restrict__ wl_bf,
                                                 const float* __restrict__ bl,
                                                 const ushort* __restrict__ wr_bf,
                                                 const float* __restrict__ alpha_p,
                                                 void* __restrict__ out_p, int n) {
    __shared__ __align__(16) ushort sA[HAS_MEAN ? 64 : 1][LDSS];
    __shared__ __align__(16) ushort sH[64][LDSS];
    __shared__ __align__(16) ushort sWl[HAS_MEAN ? 64 : 1][LDSS];
    __shared__ __align__(16) ushort sWr[64][LDSS];

    const int tid = threadIdx.x;
    const int row0 = blockIdx.x * 64;

    for (int c = tid; c < 512; c += 256) {
        int nr = c >> 3, kc = (c & 7) * 8;
        *(uint4*)&sWr[nr][kc] = *(const uint4*)&wr_bf[nr * 64 + kc];
        if (HAS_MEAN) *(uint4*)&sWl[nr][kc] = *(const uint4*)&wl_bf[nr * 64 + kc];
    }
    for (int c = tid; c < 512; c += 256) {
        int r = c >> 3, dc = (c & 7) * 8;
        int g = row0 + r;
        uint4 hv = {0, 0, 0, 0}, av = {0, 0, 0, 0};
        if (g < n) {
            hv = *(const uint4*)&hin[(size_t)g * HID + dc];
            if (HAS_MEAN) av = *(const uint4*)&mean[(size_t)g * HID + dc];
        }
        *(uint4*)&sH[r][dc] = hv;
        if (HAS_MEAN) *(uint4*)&sA[r][dc] = av;
    }
    __syncthreads();

    const int wave = tid >> 6;
    const int lane = tid & 63;
    const int quad = lane >> 4;
    const int lr = lane & 15;
    const int r0 = wave * 16;
    const float alpha = HAS_PRELU ? alpha_p[0] : 0.f;

    for (int nt = 0; nt < 4; ++nt) {
        f32x4 acc = {0.f, 0.f, 0.f, 0.f};
#pragma unroll
        for (int ks = 0; ks < 2; ++ks) {
            int k0 = ks * 32 + quad * 8;
            bf16x8 hf = *(const bf16x8*)&sH[r0 + lr][k0];
            bf16x8 wr = *(const bf16x8*)&sWr[nt * 16 + lr][k0];
            acc = __builtin_amdgcn_mfma_f32_16x16x32_bf16(hf, wr, acc, 0, 0, 0);
            if (HAS_MEAN) {
                bf16x8 af = *(const bf16x8*)&sA[r0 + lr][k0];
                bf16x8 wl = *(const bf16x8*)&sWl[nt * 16 + lr][k0];
                acc = __builtin_amdgcn_mfma_f32_16x16x32_bf16(af, wl, acc, 0, 0, 0);
            }
        }
        int col = nt * 16 + lr;
        float bias = bl[col];
#pragma unroll
        for (int r = 0; r < 4; ++r) {
            int row = r0 + quad * 4 + r;  // C/D: col=lane&15, row=(lane>>4)*4+reg [m89]
            int g = row0 + row;
            if (g < n) {
                float v = acc[r] + bias;
                if (HAS_PRELU) v = (v >= 0.f) ? v : alpha * v;
                if (OUT_F32)
                    ((float*)out_p)[(size_t)g * HID + col] = v;
                else
                    ((ushort*)out_p)[(size_t)g * HID + col] = f2bf(v);
            }
        }
    }
}

extern "C" void kernel_launch(void* const* d_in, const int* in_sizes, int n_in,
                              void* d_out, int out_size, void* d_ws, size_t ws_size,
                              hipStream_t stream) {
    const int*   x    = (const int*)d_in[0];
    const int*   src  = (const int*)d_in[1];
    const int*   dst  = src + N_EDGES;
    const float* emb  = (const float*)d_in[3];
    const float* Wl1  = (const float*)d_in[4];
    const float* bl1  = (const float*)d_in[5];
    const float* Wr1  = (const float*)d_in[6];
    const float* a1   = (const float*)d_in[7];
    const float* Wl2  = (const float*)d_in[8];
    const float* bl2  = (const float*)d_in[9];
    const float* Wr2  = (const float*)d_in[10];
    const float* a2   = (const float*)d_in[11];
    const float* Wout = (const float*)d_in[12];
    const float* bout = (const float*)d_in[13];

    char* ws = (char*)d_ws;
    int*    gh      = (int*)ws;                      // 100,352 (pad 100,416)
    int*    btot    = (int*)(ws + 100416);           // 832
    int*    bstart  = (int*)(ws + 101248);           // 832
    int*    rowptr  = (int*)(ws + 102080);           // 400,064
    ushort* wbf     = (ushort*)(ws + 502144);        // 40,960
    uint*   ebuf    = (uint*)(ws + 543104);          // 5,000,000
    int*    csr_src = (int*)(ws + 5543104);          // 5,000,000
    ushort* h0      = (ushort*)(ws + 10543104);      // 12.8 MB
    ushort* h1      = (ushort*)(ws + 23343104);      // 12.8 MB
    ushort* meanb   = (ushort*)(ws + 36143104);      // 12.8 MB (end: 48.9 MB)
    ushort* h2      = h0;                            // h0 dead after layer-1

    ushort* wl1b  = wbf;
    ushort* wr1b  = wbf + 4096;
    ushort* wl2b  = wbf + 8192;
    ushort* wr2b  = wbf + 12288;
    ushort* woutb = wbf + 16384;

    const int gemm_blocks = (N_NODES + 63) / 64;     // 1563
    const int agg_blocks  = (N_NODES + 31) / 32;     // 3125

    embed_gather<<<(N_NODES * 16 + 255) / 256, 256, 0, stream>>>(x, emb, h0);
    wcvt<<<5, 256, 0, stream>>>(Wl1, Wr1, Wl2, Wr2, Wout, wbf);
    p1_hist<<<NBLOCK, 256, 0, stream>>>(dst, gh);
    p2_scan<<<NB, 128, 0, stream>>>(gh, btot);
    p2b_scan<<<1, 256, 0, stream>>>(btot, bstart);
    p3_scatter<<<NBLOCK, 256, 0, stream>>>(src, dst, gh, bstart, ebuf);
    p4_csr<<<NB, 256, 0, stream>>>(ebuf, bstart, rowptr, csr_src);

    // layer 1
    agg_mean<<<agg_blocks, 256, 0, stream>>>(rowptr, csr_src, h0, meanb);
    gemm_mfma<true, true, false><<<gemm_blocks, 256, 0, stream>>>(
        meanb, h0, wl1b, bl1, wr1b, a1, h1, N_NODES);
    // layer 2
    agg_mean<<<agg_blocks, 256, 0, stream>>>(rowptr, csr_src, h1, meanb);
    gemm_mfma<true, true, false><<<gemm_blocks, 256, 0, stream>>>(
        meanb, h1, wl2b, bl2, wr2b, a2, h2, N_NODES);
    // output projection: float32 output
    gemm_mfma<false, false, true><<<gemm_blocks, 256, 0, stream>>>(
        meanb, h2, woutb, bout, woutb, a1, d_out, N_NODES);
}